// Round 1
// baseline (811.473 us; speedup 1.0000x reference)
//
#include <hip/hip_runtime.h>
#include <hip/hip_fp8.h>
#include <cstdio>
#include <cstdint>

// Problem dims (B=4 batch folded into rows)
#define K_DIM 4096
#define N_DIM 4096

typedef float v4f __attribute__((ext_vector_type(4)));

// ---------------------------------------------------------------- amax ------
__global__ void amax_kernel(const float4* __restrict__ x, int n4,
                            unsigned* __restrict__ out) {
  int i = blockIdx.x * blockDim.x + threadIdx.x;
  int stride = gridDim.x * blockDim.x;
  float m = 0.f;
  for (; i < n4; i += stride) {
    float4 v = x[i];
    m = fmaxf(m, fmaxf(fmaxf(fabsf(v.x), fabsf(v.y)),
                       fmaxf(fabsf(v.z), fabsf(v.w))));
  }
#pragma unroll
  for (int off = 32; off > 0; off >>= 1)
    m = fmaxf(m, __shfl_down(m, off, 64));
  __shared__ float wred[4];
  int lane = threadIdx.x & 63, wid = threadIdx.x >> 6;
  if (lane == 0) wred[wid] = m;
  __syncthreads();
  if (threadIdx.x == 0) {
    m = fmaxf(fmaxf(wred[0], wred[1]), fmaxf(wred[2], wred[3]));
    atomicMax(out, __float_as_uint(m));  // bit-compare valid: m >= 0
  }
}

__device__ __forceinline__ float load_scale(const unsigned* p) {
  // matches reference: scale = max(amax / 448.0, 1e-12), all fp32
  return fmaxf(__uint_as_float(*p) / 448.0f, 1e-12f);
}

__device__ __forceinline__ unsigned f2fp8(float v) {
  return (unsigned)__hip_cvt_float_to_fp8(v, __HIP_SATFINITE, __HIP_E4M3);
}

// ------------------------------------------------------------- quantize A ---
// [R][K] fp32 -> [R][K] fp8, 16 elems/thread, 16B stores
__global__ void quant1_kernel(const float4* __restrict__ x, uint4* __restrict__ q,
                              const unsigned* __restrict__ amax_bits, int n16) {
  float s = load_scale(amax_bits);
  int i = blockIdx.x * blockDim.x + threadIdx.x;
  int stride = gridDim.x * blockDim.x;
  for (; i < n16; i += stride) {
    unsigned w[4];
#pragma unroll
    for (int j = 0; j < 4; ++j) {
      float4 v = x[i * 4 + j];
      w[j] = f2fp8(v.x / s) | (f2fp8(v.y / s) << 8) |
             (f2fp8(v.z / s) << 16) | (f2fp8(v.w / s) << 24);
    }
    uint4 r; r.x = w[0]; r.y = w[1]; r.z = w[2]; r.w = w[3];
    q[i] = r;
  }
}

// -------------------------------------------- quantize + transpose B --------
// x: [K][N] fp32 -> qt: [N][K] fp8 (so GEMM B-fragments are contiguous in K)
__global__ void quant2t_kernel(const float* __restrict__ x,
                               unsigned char* __restrict__ qt,
                               const unsigned* __restrict__ amax_bits) {
  float s = load_scale(amax_bits);
  __shared__ unsigned char tile[64][68];  // pad 68 (17 dwords, odd) -> conflict-light
  int tj = blockIdx.x & 63;  // N tile
  int ti = blockIdx.x >> 6;  // K tile
  int t = threadIdx.x;
  int c = t & 63;            // N offset within tile
  int r0 = (t >> 6) * 16;    // K offset base
#pragma unroll
  for (int rr = 0; rr < 16; ++rr) {
    int r = r0 + rr;
    float v = x[(size_t)(ti * 64 + r) * N_DIM + tj * 64 + c];
    tile[c][r] = (unsigned char)f2fp8(v / s);  // store transposed: [n][k]
  }
  __syncthreads();
  int n = t >> 2;
  int kc = (t & 3) << 4;
  const unsigned* lp = (const unsigned*)&tile[n][kc];
  uint4 v; v.x = lp[0]; v.y = lp[1]; v.z = lp[2]; v.w = lp[3];
  *(uint4*)&qt[(size_t)(tj * 64 + n) * K_DIM + ti * 64 + kc] = v;
}

// ------------------------------------------------------------------ GEMM ----
// C[R][N] = (A8[R][K] . Bt8[N][K]^T) * s1*s2  -- fp8 e4m3 MFMA, fp32 accum
// 128x128 tile, BK=64 bytes, 256 threads (4 waves, each 64x64 quadrant).
// LDS layout: As[row][c] holds A[row][c ^ ((row&3)<<4)] (16B-granular XOR
// swizzle). global_load_lds writes linearly (dest = base + lane*16), so the
// swizzle is applied on the GLOBAL source address; ds_reads apply the same XOR.
#define BM 128
#define BN 128
#define BK 64

__global__ __launch_bounds__(256)
void gemm_fp8_kernel(const unsigned char* __restrict__ A,
                     const unsigned char* __restrict__ Bt,
                     float* __restrict__ C,
                     const unsigned* __restrict__ amax_bits) {
  __shared__ __align__(16) unsigned char As[BM * BK];
  __shared__ __align__(16) unsigned char Bs[BN * BK];

  float scale = load_scale(amax_bits) * load_scale(amax_bits + 1);

  const int nbn = N_DIM / BN;  // 32 col tiles
  int bid = blockIdx.x;
  int brow = (bid / nbn) * BM;
  int bcol = (bid % nbn) * BN;

  int t = threadIdx.x;
  int lane = t & 63;
  int wid = t >> 6;
  int wr = (wid >> 1) * 64;  // wave row quadrant
  int wc = (wid & 1) * 64;   // wave col quadrant
  int fr = lane & 15;        // fragment row/col within 16
  int kq = lane >> 4;        // k-quarter 0..3

  // --- staging addresses (2 x 16B chunks per thread per tile per matrix)
  int o0 = t * 16;                  // linear LDS dest, chunk 0 (rows 0..63)
  int row0 = o0 >> 6, cb0 = o0 & 63;
  int sw0 = cb0 ^ ((row0 & 3) << 4);  // inverse-swizzled source column
  int o1 = o0 + 4096;               // chunk 1 (rows 64..127)
  int row1 = row0 + 64;
  int sw1 = cb0 ^ ((row1 & 3) << 4);

  const unsigned char* ga0 = A + (size_t)(brow + row0) * K_DIM + sw0;
  const unsigned char* ga1 = A + (size_t)(brow + row1) * K_DIM + sw1;
  const unsigned char* gb0 = Bt + (size_t)(bcol + row0) * K_DIM + sw0;
  const unsigned char* gb1 = Bt + (size_t)(bcol + row1) * K_DIM + sw1;

  // --- ds_read offsets: row = quadrant + f*16 + fr ; k = kk*32 + kq*8
  int swz = (fr & 3) << 4;  // (row&3)<<4 — same for every f given lane
  int aoff[4], boff[4];
#pragma unroll
  for (int f = 0; f < 4; ++f) {
    aoff[f] = (wr + f * 16 + fr) * BK;
    boff[f] = (wc + f * 16 + fr) * BK;
  }

  v4f acc[4][4] = {};

  for (int kt = 0; kt < K_DIM; kt += BK) {
    __builtin_amdgcn_global_load_lds(
        (const __attribute__((address_space(1))) void*)(ga0 + kt),
        (__attribute__((address_space(3))) void*)(As + o0), 16, 0, 0);
    __builtin_amdgcn_global_load_lds(
        (const __attribute__((address_space(1))) void*)(ga1 + kt),
        (__attribute__((address_space(3))) void*)(As + o1), 16, 0, 0);
    __builtin_amdgcn_global_load_lds(
        (const __attribute__((address_space(1))) void*)(gb0 + kt),
        (__attribute__((address_space(3))) void*)(Bs + o0), 16, 0, 0);
    __builtin_amdgcn_global_load_lds(
        (const __attribute__((address_space(1))) void*)(gb1 + kt),
        (__attribute__((address_space(3))) void*)(Bs + o1), 16, 0, 0);

    __syncthreads();  // drains vmcnt before any wave reads LDS

#pragma unroll
    for (int kk = 0; kk < 2; ++kk) {
      int kb = (kk * 32 + kq * 8) ^ swz;
      long af[4], bf[4];
#pragma unroll
      for (int f = 0; f < 4; ++f) {
        af[f] = *(const long*)(As + aoff[f] + kb);
        bf[f] = *(const long*)(Bs + boff[f] + kb);
      }
#pragma unroll
      for (int m = 0; m < 4; ++m)
#pragma unroll
        for (int n = 0; n < 4; ++n)
          acc[m][n] = __builtin_amdgcn_mfma_f32_16x16x32_fp8_fp8(
              af[m], bf[n], acc[m][n], 0, 0, 0);
    }
    __syncthreads();  // before next tile overwrites LDS
  }

  // epilogue: C/D layout col = lane&15, row = (lane>>4)*4 + reg
  float* Cp = C + (size_t)(brow + wr + kq * 4) * N_DIM + (bcol + wc + fr);
#pragma unroll
  for (int m = 0; m < 4; ++m)
#pragma unroll
    for (int r = 0; r < 4; ++r) {
      float* crow = Cp + (size_t)(m * 16 + r) * N_DIM;
#pragma unroll
      for (int n = 0; n < 4; ++n) crow[n * 16] = acc[m][n][r] * scale;
    }
}

// ----------------------------------------------------------------- launch ---
extern "C" void kernel_launch(void* const* d_in, const int* in_sizes, int n_in,
                              void* d_out, int out_size, void* d_ws,
                              size_t ws_size, hipStream_t stream) {
  const float* in1 = (const float*)d_in[0];
  const float* in2 = (const float*)d_in[1];
  float* out = (float*)d_out;
  unsigned char* ws = (unsigned char*)d_ws;

  const int R = in_sizes[0] / K_DIM;  // 16384 (batch*M)
  const size_t qa_bytes = (size_t)R * K_DIM;
  const size_t qb_bytes = (size_t)N_DIM * K_DIM;
  const size_t need = 256 + qa_bytes + qb_bytes;
  if (ws_size < need) {
    fprintf(stderr, "kernel_launch: ws_size %zu < needed %zu\n", ws_size, need);
    return;
  }
  unsigned* amax = (unsigned*)ws;
  unsigned char* q1 = ws + 256;
  unsigned char* q2t = q1 + qa_bytes;

  hipMemsetAsync(ws, 0, 8, stream);  // reset amax slots every call
  amax_kernel<<<2048, 256, 0, stream>>>((const float4*)in1, in_sizes[0] / 4, amax);
  amax_kernel<<<1024, 256, 0, stream>>>((const float4*)in2, in_sizes[1] / 4, amax + 1);
  quant1_kernel<<<2048, 256, 0, stream>>>((const float4*)in1, (uint4*)q1, amax,
                                          in_sizes[0] / 16);
  quant2t_kernel<<<(K_DIM / 64) * (N_DIM / 64), 256, 0, stream>>>(in2, q2t, amax + 1);
  gemm_fp8_kernel<<<(R / BM) * (N_DIM / BN), 256, 0, stream>>>(q1, q2t, out, amax);
}

// Round 2
// 585.633 us; speedup vs baseline: 1.3856x; 1.3856x over previous
//
#include <hip/hip_runtime.h>
#include <hip/hip_fp8.h>
#include <cstdio>
#include <cstdint>

#define K_DIM 4096
#define N_DIM 4096
#define BKB 64                 // K-bytes per LDS tile
#define NT (K_DIM / BKB)       // 64 K-tiles

typedef float v4f __attribute__((ext_vector_type(4)));
typedef long v2l __attribute__((ext_vector_type(2)));

// ---------------------------------------------------------------- amax ------
__global__ void amax_kernel(const float4* __restrict__ x, int n4,
                            unsigned* __restrict__ out) {
  int i = blockIdx.x * blockDim.x + threadIdx.x;
  int stride = gridDim.x * blockDim.x;
  float m = 0.f;
  for (; i < n4; i += stride) {
    float4 v = x[i];
    m = fmaxf(m, fmaxf(fmaxf(fabsf(v.x), fabsf(v.y)),
                       fmaxf(fabsf(v.z), fabsf(v.w))));
  }
#pragma unroll
  for (int off = 32; off > 0; off >>= 1)
    m = fmaxf(m, __shfl_down(m, off, 64));
  __shared__ float wred[4];
  int lane = threadIdx.x & 63, wid = threadIdx.x >> 6;
  if (lane == 0) wred[wid] = m;
  __syncthreads();
  if (threadIdx.x == 0) {
    m = fmaxf(fmaxf(wred[0], wred[1]), fmaxf(wred[2], wred[3]));
    atomicMax(out, __float_as_uint(m));  // bit-compare valid: m >= 0
  }
}

__device__ __forceinline__ float load_scale(const unsigned* p) {
  return fmaxf(__uint_as_float(*p) / 448.0f, 1e-12f);
}

__device__ __forceinline__ unsigned f2fp8(float v) {
  return (unsigned)__hip_cvt_float_to_fp8(v, __HIP_SATFINITE, __HIP_E4M3);
}

// ------------------------------------------------------------- quantize A ---
__global__ void quant1_kernel(const float4* __restrict__ x, uint4* __restrict__ q,
                              const unsigned* __restrict__ amax_bits, int n16) {
  float s = load_scale(amax_bits);
  int i = blockIdx.x * blockDim.x + threadIdx.x;
  int stride = gridDim.x * blockDim.x;
  for (; i < n16; i += stride) {
    unsigned w[4];
#pragma unroll
    for (int j = 0; j < 4; ++j) {
      float4 v = x[i * 4 + j];
      w[j] = f2fp8(v.x / s) | (f2fp8(v.y / s) << 8) |
             (f2fp8(v.z / s) << 16) | (f2fp8(v.w / s) << 24);
    }
    uint4 r; r.x = w[0]; r.y = w[1]; r.z = w[2]; r.w = w[3];
    q[i] = r;
  }
}

// -------------------------------------------- quantize + transpose B --------
__global__ void quant2t_kernel(const float* __restrict__ x,
                               unsigned char* __restrict__ qt,
                               const unsigned* __restrict__ amax_bits) {
  float s = load_scale(amax_bits);
  __shared__ unsigned char tile[64][68];
  int tj = blockIdx.x & 63;
  int ti = blockIdx.x >> 6;
  int t = threadIdx.x;
  int c = t & 63;
  int r0 = (t >> 6) * 16;
#pragma unroll
  for (int rr = 0; rr < 16; ++rr) {
    int r = r0 + rr;
    float v = x[(size_t)(ti * 64 + r) * N_DIM + tj * 64 + c];
    tile[c][r] = (unsigned char)f2fp8(v / s);
  }
  __syncthreads();
  int n = t >> 2;
  int kc = (t & 3) << 4;
  const unsigned* lp = (const unsigned*)&tile[n][kc];
  uint4 v; v.x = lp[0]; v.y = lp[1]; v.z = lp[2]; v.w = lp[3];
  *(uint4*)&qt[(size_t)(tj * 64 + n) * K_DIM + ti * 64 + kc] = v;
}

// ------------------------------------------------------------------ GEMM ----
// 256x256 tile, 8 waves (2Mx4N), BK=64B, ring-4 LDS double... quad-buffer.
// LDS per buffer: A[256][64] (16K) + B[256][64] (16K).  Swizzle: within a
// 128B macro-row (row pair), (row,kq)->slot u^(macro&7), u=((row&1)<<2)|kq.
// global_load_lds dest is linear; source col pre-swizzled (involution).
#define GLOAD(src, dst)                                              \
  __builtin_amdgcn_global_load_lds(                                  \
      (const __attribute__((address_space(1))) void*)(src),          \
      (__attribute__((address_space(3))) void*)(dst), 16, 0, 0)

__global__ __launch_bounds__(512, 2)
void gemm_fp8_kernel(const unsigned char* __restrict__ A,
                     const unsigned char* __restrict__ Bt,
                     float* __restrict__ C,
                     const unsigned* __restrict__ amax_bits) {
  __shared__ __align__(16) unsigned char lds[4][32768];

  int bid = blockIdx.x;
  int nwg = gridDim.x;                    // 1024, %8 == 0
  int swz = (bid & 7) * (nwg >> 3) + (bid >> 3);
  int brow = (swz >> 4) * 256;
  int bcol = (swz & 15) * 256;

  int t = threadIdx.x;
  int lane = t & 63, wid = t >> 6;
  int wm = wid >> 2, wn = wid & 3;        // wave quadrant: 2M x 4N
  int fr = lane & 15, kq = lane >> 4;

  // staging constants: dest o = t*16 (+slab*8192) -> row 2*(t>>3)+(u>>2), col (u&3)*16
  int su = (t & 7) ^ ((t >> 3) & 7);
  int srow = 2 * (t >> 3) + (su >> 2);
  int scol = (su & 3) << 4;
  int sdst = t << 4;
  const unsigned char* gA0 = A + (size_t)(brow + srow) * K_DIM + scol;
  const unsigned char* gA1 = gA0 + (size_t)128 * K_DIM;
  const unsigned char* gB0 = Bt + (size_t)(bcol + srow) * K_DIM + scol;
  const unsigned char* gB1 = gB0 + (size_t)128 * K_DIM;

  // ds_read constants: frag row r -> addr (r>>1)*128 + slot*16, slot const/lane
  int slot = ((((fr & 1) << 2) | kq) ^ (fr >> 1)) << 4;
  int abase = (wm * 64 + (fr >> 1)) * 128 + slot;           // + frag*1024
  int bbase = 16384 + (wn * 32 + (fr >> 1)) * 128 + slot;   // + frag*1024

  auto STAGE = [&](int T, int part) {
    unsigned char* dst = &lds[T & 3][part * 8192] + sdst;
    int koff = T * BKB;
    const unsigned char* src = part == 0   ? gA0 + koff
                               : part == 1 ? gA1 + koff
                               : part == 2 ? gB0 + koff
                                           : gB1 + koff;
    GLOAD(src, dst);
  };

  v4f acc[8][4] = {};

  // prologue: stage tiles 0,1,2 (12 insts), drain to 8 -> tile 0 landed
#pragma unroll
  for (int T = 0; T < 3; ++T)
#pragma unroll
    for (int p = 0; p < 4; ++p) STAGE(T, p);
  asm volatile("s_waitcnt vmcnt(8)" ::: "memory");
  __builtin_amdgcn_s_barrier();

  for (int T = 0; T < NT; ++T) {
    const unsigned char* buf = lds[T & 3];
    bool st = (T + 3) < NT;
    v2l a[4], b[2];

    // ---- phase 0: quadrant (mh=0, nh=0) — read A frags 0-3, B frags 0-1
#pragma unroll
    for (int m = 0; m < 4; ++m) a[m] = *(const v2l*)(buf + abase + m * 1024);
#pragma unroll
    for (int n = 0; n < 2; ++n) b[n] = *(const v2l*)(buf + bbase + n * 1024);
    if (st) STAGE(T + 3, 0);
    __builtin_amdgcn_s_barrier();
    __builtin_amdgcn_s_setprio(1);
#pragma unroll
    for (int m = 0; m < 4; ++m)
#pragma unroll
      for (int n = 0; n < 2; ++n) {
        acc[m][n] = __builtin_amdgcn_mfma_f32_16x16x32_fp8_fp8(a[m][0], b[n][0], acc[m][n], 0, 0, 0);
        acc[m][n] = __builtin_amdgcn_mfma_f32_16x16x32_fp8_fp8(a[m][1], b[n][1], acc[m][n], 0, 0, 0);
      }
    __builtin_amdgcn_s_setprio(0);
    __builtin_amdgcn_s_barrier();

    // ---- phase 1: (mh=0, nh=1) — reuse A, read B frags 2-3
#pragma unroll
    for (int n = 0; n < 2; ++n) b[n] = *(const v2l*)(buf + bbase + (2 + n) * 1024);
    if (st) STAGE(T + 3, 1);
    __builtin_amdgcn_s_barrier();
    __builtin_amdgcn_s_setprio(1);
#pragma unroll
    for (int m = 0; m < 4; ++m)
#pragma unroll
      for (int n = 0; n < 2; ++n) {
        acc[m][2 + n] = __builtin_amdgcn_mfma_f32_16x16x32_fp8_fp8(a[m][0], b[n][0], acc[m][2 + n], 0, 0, 0);
        acc[m][2 + n] = __builtin_amdgcn_mfma_f32_16x16x32_fp8_fp8(a[m][1], b[n][1], acc[m][2 + n], 0, 0, 0);
      }
    __builtin_amdgcn_s_setprio(0);
    __builtin_amdgcn_s_barrier();

    // ---- phase 2: (mh=1, nh=1) — reuse B, read A frags 4-7
#pragma unroll
    for (int m = 0; m < 4; ++m) a[m] = *(const v2l*)(buf + abase + (4 + m) * 1024);
    if (st) STAGE(T + 3, 2);
    __builtin_amdgcn_s_barrier();
    __builtin_amdgcn_s_setprio(1);
#pragma unroll
    for (int m = 0; m < 4; ++m)
#pragma unroll
      for (int n = 0; n < 2; ++n) {
        acc[4 + m][2 + n] = __builtin_amdgcn_mfma_f32_16x16x32_fp8_fp8(a[m][0], b[n][0], acc[4 + m][2 + n], 0, 0, 0);
        acc[4 + m][2 + n] = __builtin_amdgcn_mfma_f32_16x16x32_fp8_fp8(a[m][1], b[n][1], acc[4 + m][2 + n], 0, 0, 0);
      }
    __builtin_amdgcn_s_setprio(0);
    __builtin_amdgcn_s_barrier();

    // ---- phase 3: (mh=1, nh=0) — reuse A, read B frags 0-1
#pragma unroll
    for (int n = 0; n < 2; ++n) b[n] = *(const v2l*)(buf + bbase + n * 1024);
    if (st) STAGE(T + 3, 3);
    __builtin_amdgcn_s_barrier();
    __builtin_amdgcn_s_setprio(1);
#pragma unroll
    for (int m = 0; m < 4; ++m)
#pragma unroll
      for (int n = 0; n < 2; ++n) {
        acc[4 + m][n] = __builtin_amdgcn_mfma_f32_16x16x32_fp8_fp8(a[m][0], b[n][0], acc[4 + m][n], 0, 0, 0);
        acc[4 + m][n] = __builtin_amdgcn_mfma_f32_16x16x32_fp8_fp8(a[m][1], b[n][1], acc[4 + m][n], 0, 0, 0);
      }
    __builtin_amdgcn_s_setprio(0);

    // tile boundary: ensure our LDS reads retired, then counted vmcnt so the
    // NEXT tile's data (staged 3 tiles ago) has landed. Never 0 until the end.
    asm volatile("s_waitcnt lgkmcnt(0)" ::: "memory");
    __builtin_amdgcn_sched_barrier(0);
    if (T < NT - 3) {
      asm volatile("s_waitcnt vmcnt(8)" ::: "memory");
    } else if (T == NT - 3) {
      asm volatile("s_waitcnt vmcnt(4)" ::: "memory");
    } else if (T == NT - 2) {
      asm volatile("s_waitcnt vmcnt(0)" ::: "memory");
    }
    __builtin_amdgcn_s_barrier();
  }

  // epilogue: C/D map col=lane&15, row=(lane>>4)*4+reg (dtype-independent)
  float scale = load_scale(amax_bits) * load_scale(amax_bits + 1);
  float* Cp = C + (size_t)(brow + wm * 128 + kq * 4) * N_DIM + (bcol + wn * 64 + fr);
#pragma unroll
  for (int m8 = 0; m8 < 8; ++m8)
#pragma unroll
    for (int r = 0; r < 4; ++r) {
      float* crow = Cp + (size_t)(m8 * 16 + r) * N_DIM;
#pragma unroll
      for (int j = 0; j < 4; ++j) crow[j * 16] = acc[m8][j][r] * scale;
    }
}

// ----------------------------------------------------------------- launch ---
extern "C" void kernel_launch(void* const* d_in, const int* in_sizes, int n_in,
                              void* d_out, int out_size, void* d_ws,
                              size_t ws_size, hipStream_t stream) {
  const float* in1 = (const float*)d_in[0];
  const float* in2 = (const float*)d_in[1];
  float* out = (float*)d_out;
  unsigned char* ws = (unsigned char*)d_ws;

  const int R = in_sizes[0] / K_DIM;  // 16384
  const size_t qa_bytes = (size_t)R * K_DIM;
  const size_t qb_bytes = (size_t)N_DIM * K_DIM;
  const size_t need = 256 + qa_bytes + qb_bytes;
  if (ws_size < need) {
    fprintf(stderr, "kernel_launch: ws_size %zu < needed %zu\n", ws_size, need);
    return;
  }
  unsigned* amax = (unsigned*)ws;
  unsigned char* q1 = ws + 256;
  unsigned char* q2t = q1 + qa_bytes;

  hipMemsetAsync(ws, 0, 8, stream);
  amax_kernel<<<2048, 256, 0, stream>>>((const float4*)in1, in_sizes[0] / 4, amax);
  amax_kernel<<<1024, 256, 0, stream>>>((const float4*)in2, in_sizes[1] / 4, amax + 1);
  quant1_kernel<<<2048, 256, 0, stream>>>((const float4*)in1, (uint4*)q1, amax,
                                          in_sizes[0] / 16);
  quant2t_kernel<<<(K_DIM / 64) * (N_DIM / 64), 256, 0, stream>>>(in2, q2t, amax + 1);
  gemm_fp8_kernel<<<(R / 256) * (N_DIM / 256), 512, 0, stream>>>(q1, q2t, out, amax);
}

// Round 3
// 464.494 us; speedup vs baseline: 1.7470x; 1.2608x over previous
//
#include <hip/hip_runtime.h>
#include <hip/hip_fp8.h>
#include <cstdio>
#include <cstdint>

#define K_DIM 4096
#define N_DIM 4096
#define BKB 64                 // K-bytes per LDS tile
#define NT (K_DIM / BKB)       // 64 K-tiles

typedef int v4i __attribute__((ext_vector_type(4)));
typedef int v8i __attribute__((ext_vector_type(8)));
typedef float v16f __attribute__((ext_vector_type(16)));

// ---------------------------------------------------------------- amax ------
__global__ void amax_kernel(const float4* __restrict__ x, int n4,
                            unsigned* __restrict__ out) {
  int i = blockIdx.x * blockDim.x + threadIdx.x;
  int stride = gridDim.x * blockDim.x;
  float m = 0.f;
  for (; i < n4; i += stride) {
    float4 v = x[i];
    m = fmaxf(m, fmaxf(fmaxf(fabsf(v.x), fabsf(v.y)),
                       fmaxf(fabsf(v.z), fabsf(v.w))));
  }
#pragma unroll
  for (int off = 32; off > 0; off >>= 1)
    m = fmaxf(m, __shfl_down(m, off, 64));
  __shared__ float wred[4];
  int lane = threadIdx.x & 63, wid = threadIdx.x >> 6;
  if (lane == 0) wred[wid] = m;
  __syncthreads();
  if (threadIdx.x == 0) {
    m = fmaxf(fmaxf(wred[0], wred[1]), fmaxf(wred[2], wred[3]));
    atomicMax(out, __float_as_uint(m));  // bit-compare valid: m >= 0
  }
}

__device__ __forceinline__ float load_scale(const unsigned* p) {
  return fmaxf(__uint_as_float(*p) / 448.0f, 1e-12f);
}

__device__ __forceinline__ unsigned f2fp8(float v) {
  return (unsigned)__hip_cvt_float_to_fp8(v, __HIP_SATFINITE, __HIP_E4M3);
}

// ------------------------------------------------------------- quantize A ---
__global__ void quant1_kernel(const float4* __restrict__ x, uint4* __restrict__ q,
                              const unsigned* __restrict__ amax_bits, int n16) {
  float s = load_scale(amax_bits);
  int i = blockIdx.x * blockDim.x + threadIdx.x;
  int stride = gridDim.x * blockDim.x;
  for (; i < n16; i += stride) {
    unsigned w[4];
#pragma unroll
    for (int j = 0; j < 4; ++j) {
      float4 v = x[i * 4 + j];
      w[j] = f2fp8(v.x / s) | (f2fp8(v.y / s) << 8) |
             (f2fp8(v.z / s) << 16) | (f2fp8(v.w / s) << 24);
    }
    uint4 r; r.x = w[0]; r.y = w[1]; r.z = w[2]; r.w = w[3];
    q[i] = r;
  }
}

// -------------------------------------------- quantize + transpose B --------
__global__ void quant2t_kernel(const float* __restrict__ x,
                               unsigned char* __restrict__ qt,
                               const unsigned* __restrict__ amax_bits) {
  float s = load_scale(amax_bits);
  __shared__ unsigned char tile[64][68];
  int tj = blockIdx.x & 63;
  int ti = blockIdx.x >> 6;
  int t = threadIdx.x;
  int c = t & 63;
  int r0 = (t >> 6) * 16;
#pragma unroll
  for (int rr = 0; rr < 16; ++rr) {
    int r = r0 + rr;
    float v = x[(size_t)(ti * 64 + r) * N_DIM + tj * 64 + c];
    tile[c][r] = (unsigned char)f2fp8(v / s);
  }
  __syncthreads();
  int n = t >> 2;
  int kc = (t & 3) << 4;
  const unsigned* lp = (const unsigned*)&tile[n][kc];
  uint4 v; v.x = lp[0]; v.y = lp[1]; v.z = lp[2]; v.w = lp[3];
  *(uint4*)&qt[(size_t)(tj * 64 + n) * K_DIM + ti * 64 + kc] = v;
}

// ------------------------------------------------------------------ GEMM ----
// 256x256 tile, 8 waves (2Mx4N), BK=64B, ring-4 LDS, MX-scaled fp8 MFMA
// (scale=1.0 exact) at 2x the non-scaled fp8 rate.
// Physical LDS layout (unchanged, conflict-free verified): logical (row r,
// byte c) at (r>>1)*128 + (((((r&1)<<2)|(c>>4)) ^ ((r>>1)&7))<<4) + (c&15).
// Staging is linear-dest global_load_lds with pre-swizzled source (rule #21).
#define GLOAD(src, dst)                                              \
  __builtin_amdgcn_global_load_lds(                                  \
      (const __attribute__((address_space(1))) void*)(src),          \
      (__attribute__((address_space(3))) void*)(dst), 16, 0, 0)

#define MFMA_SC(a, b, c)                                             \
  __builtin_amdgcn_mfma_scale_f32_32x32x64_f8f6f4(a, b, c, 0, 0, 0, 127, 0, 127)

__global__ __launch_bounds__(512, 2)
void gemm_fp8_kernel(const unsigned char* __restrict__ A,
                     const unsigned char* __restrict__ Bt,
                     float* __restrict__ C,
                     const unsigned* __restrict__ amax_bits) {
  __shared__ __align__(16) unsigned char lds[4][32768];

  int bid = blockIdx.x;
  int nwg = gridDim.x;                    // 1024, %8 == 0
  int swz = (bid & 7) * (nwg >> 3) + (bid >> 3);
  int brow = (swz >> 4) * 256;
  int bcol = (swz & 15) * 256;

  int t = threadIdx.x;
  int lane = t & 63, wid = t >> 6;
  int wm = wid >> 2, wn = wid & 3;        // wave quadrant: 2M x 4N
  int r5 = lane & 31;                     // row/col within 32x32 subtile
  int khalf = lane >> 5;                  // k-half selector (32B each)

  // staging constants (identical to round 2): dest linear, source pre-swizzled
  int su = (t & 7) ^ ((t >> 3) & 7);
  int srow = 2 * (t >> 3) + (su >> 2);
  int scol = (su & 3) << 4;
  int sdst = t << 4;
  const unsigned char* gA0 = A + (size_t)(brow + srow) * K_DIM + scol;
  const unsigned char* gA1 = gA0 + (size_t)128 * K_DIM;
  const unsigned char* gB0 = Bt + (size_t)(bcol + srow) * K_DIM + scol;
  const unsigned char* gB1 = gB0 + (size_t)128 * K_DIM;

  // fragment read constants: lane reads row base+r5, bytes khalf*32..+31
  // as two b128 at swizzled slots kq0 = 2*khalf, kq0+1.
  int kq0 = khalf << 1;
  int mac = (r5 >> 1) & 7;
  int slot0 = (((((r5 & 1) << 2) | kq0) ^ mac) << 4);
  int slot1 = (((((r5 & 1) << 2) | (kq0 + 1)) ^ mac) << 4);
  int arow = (wm * 64 + (r5 >> 1)) * 128;           // + m*2048 per subtile
  int brow_o = 16384 + (wn * 32 + (r5 >> 1)) * 128; // + n*2048 per subtile

  auto STAGE = [&](int T, int part) {
    unsigned char* dst = &lds[T & 3][part * 8192] + sdst;
    int koff = T * BKB;
    const unsigned char* src = part == 0   ? gA0 + koff
                               : part == 1 ? gA1 + koff
                               : part == 2 ? gB0 + koff
                                           : gB1 + koff;
    GLOAD(src, dst);
  };

  auto FRAG = [&](const unsigned char* buf, int base) -> v8i {
    v4i lo = *(const v4i*)(buf + base + slot0);
    v4i hi = *(const v4i*)(buf + base + slot1);
    return __builtin_shufflevector(lo, hi, 0, 1, 2, 3, 4, 5, 6, 7);
  };

  v16f acc[4][2] = {};

  // prologue: stage tiles 0,1,2 (12 loads), wait down to 8 -> tile 0 landed
#pragma unroll
  for (int T = 0; T < 3; ++T)
#pragma unroll
    for (int p = 0; p < 4; ++p) STAGE(T, p);
  asm volatile("s_waitcnt vmcnt(8)" ::: "memory");
  __builtin_amdgcn_s_barrier();

  for (int T = 0; T < NT; ++T) {
    const unsigned char* buf = lds[T & 3];
    bool st = (T + 3) < NT;

    // ---- phase 0: A subtiles 0,1 x B subtiles 0,1
    v8i a0 = FRAG(buf, arow);
    v8i a1 = FRAG(buf, arow + 2048);
    v8i b0 = FRAG(buf, brow_o);
    v8i b1 = FRAG(buf, brow_o + 2048);
    if (st) { STAGE(T + 3, 0); STAGE(T + 3, 1); }
    __builtin_amdgcn_s_barrier();
    __builtin_amdgcn_s_setprio(1);
    acc[0][0] = MFMA_SC(a0, b0, acc[0][0]);
    acc[0][1] = MFMA_SC(a0, b1, acc[0][1]);
    acc[1][0] = MFMA_SC(a1, b0, acc[1][0]);
    acc[1][1] = MFMA_SC(a1, b1, acc[1][1]);
    __builtin_amdgcn_s_setprio(0);
    __builtin_amdgcn_s_barrier();

    // ---- phase 1: A subtiles 2,3 x B subtiles 0,1 (B reused in regs)
    v8i a2 = FRAG(buf, arow + 2 * 2048);
    v8i a3 = FRAG(buf, arow + 3 * 2048);
    if (st) { STAGE(T + 3, 2); STAGE(T + 3, 3); }
    __builtin_amdgcn_s_barrier();
    __builtin_amdgcn_s_setprio(1);
    acc[2][0] = MFMA_SC(a2, b0, acc[2][0]);
    acc[2][1] = MFMA_SC(a2, b1, acc[2][1]);
    acc[3][0] = MFMA_SC(a3, b0, acc[3][0]);
    acc[3][1] = MFMA_SC(a3, b1, acc[3][1]);
    __builtin_amdgcn_s_setprio(0);

    // tile boundary: our LDS reads must retire (next iter's staging of T+4
    // overwrites this ring slot), then counted vmcnt so tile T+1 has landed.
    asm volatile("s_waitcnt lgkmcnt(0)" ::: "memory");
    __builtin_amdgcn_sched_barrier(0);
    if (T < NT - 3) {
      asm volatile("s_waitcnt vmcnt(8)" ::: "memory");
    } else if (T == NT - 3) {
      asm volatile("s_waitcnt vmcnt(4)" ::: "memory");
    } else if (T == NT - 2) {
      asm volatile("s_waitcnt vmcnt(0)" ::: "memory");
    }
    __builtin_amdgcn_s_barrier();
  }

  // epilogue: 32x32 C/D map: col = lane&31, row = (reg&3)+8*(reg>>2)+4*(lane>>5)
  float scale = load_scale(amax_bits) * load_scale(amax_bits + 1);
  float* Cp = C + (size_t)(brow + wm * 128 + khalf * 4) * N_DIM +
              (bcol + wn * 64 + r5);
#pragma unroll
  for (int m = 0; m < 4; ++m)
#pragma unroll
    for (int r = 0; r < 16; ++r) {
      size_t ro = (size_t)(m * 32 + (r & 3) + 8 * (r >> 2)) * N_DIM;
#pragma unroll
      for (int n = 0; n < 2; ++n)
        Cp[ro + n * 32] = acc[m][n][r] * scale;
    }
}

// ----------------------------------------------------------------- launch ---
extern "C" void kernel_launch(void* const* d_in, const int* in_sizes, int n_in,
                              void* d_out, int out_size, void* d_ws,
                              size_t ws_size, hipStream_t stream) {
  const float* in1 = (const float*)d_in[0];
  const float* in2 = (const float*)d_in[1];
  float* out = (float*)d_out;
  unsigned char* ws = (unsigned char*)d_ws;

  const int R = in_sizes[0] / K_DIM;  // 16384
  const size_t qa_bytes = (size_t)R * K_DIM;
  const size_t qb_bytes = (size_t)N_DIM * K_DIM;
  const size_t need = 256 + qa_bytes + qb_bytes;
  if (ws_size < need) {
    fprintf(stderr, "kernel_launch: ws_size %zu < needed %zu\n", ws_size, need);
    return;
  }
  unsigned* amax = (unsigned*)ws;
  unsigned char* q1 = ws + 256;
  unsigned char* q2t = q1 + qa_bytes;

  hipMemsetAsync(ws, 0, 8, stream);
  amax_kernel<<<2048, 256, 0, stream>>>((const float4*)in1, in_sizes[0] / 4, amax);
  amax_kernel<<<1024, 256, 0, stream>>>((const float4*)in2, in_sizes[1] / 4, amax + 1);
  quant1_kernel<<<2048, 256, 0, stream>>>((const float4*)in1, (uint4*)q1, amax,
                                          in_sizes[0] / 16);
  quant2t_kernel<<<(K_DIM / 64) * (N_DIM / 64), 256, 0, stream>>>(in2, q2t, amax + 1);
  gemm_fp8_kernel<<<(R / 256) * (N_DIM / 256), 512, 0, stream>>>(q1, q2t, out, amax);
}